// Round 1
// baseline (4592.368 us; speedup 1.0000x reference)
//
#include <hip/hip_runtime.h>
#include <hip/hip_bf16.h>
#include <stdint.h>

typedef unsigned short u16;
typedef unsigned int u32;
typedef unsigned long long u64;
typedef float f32x4 __attribute__((ext_vector_type(4)));
typedef float f32x2 __attribute__((ext_vector_type(2)));
typedef u32 u32x4 __attribute__((ext_vector_type(4)));
typedef __bf16 bf16x8 __attribute__((ext_vector_type(8)));

#define MFMA16(A, B, C) __builtin_amdgcn_mfma_f32_16x16x32_bf16((A), (B), (C), 0, 0, 0)

__device__ __forceinline__ u16 f2bf(float f) {
  u32 u = __float_as_uint(f);
  u32 r = (u + 0x7fffu + ((u >> 16) & 1u)) >> 16;
  return (u16)r;
}
__device__ __forceinline__ bf16x8 ld8(const u16* p) {
  return __builtin_bit_cast(bf16x8, *(const u32x4*)p);
}
// fast sigmoid/tanh via v_exp; safe for all finite inputs
__device__ __forceinline__ float sigm(float x) { return 1.f / (1.f + __expf(-x)); }
__device__ __forceinline__ float tanh_f(float x) {
  float a = fabsf(x);
  float e = __expf(-2.f * a);          // e in (0,1], never overflows
  float r = (1.f - e) / (1.f + e);
  return copysignf(r, x);
}

// ---------------------------------------------------------------------------
// cast f32 -> bf16 (RNE), 4 elems/thread
// ---------------------------------------------------------------------------
__global__ __launch_bounds__(256) void castbf(const float* __restrict__ s,
                                              u16* __restrict__ d, int n4) {
  int i = blockIdx.x * 256 + threadIdx.x;
  if (i >= n4) return;
  f32x4 v = *(const f32x4*)(s + (size_t)i * 4);
  union { u16 t[4]; u64 v; } u;
#pragma unroll
  for (int e = 0; e < 4; e++) u.t[e] = f2bf(v[e]);
  *(u64*)(d + (size_t)i * 4) = u.v;
}

// ---------------------------------------------------------------------------
// K1: conv tower (8x conv+instance-norm, residuals) + feat + Z0 = feat@Wih.T
// one workgroup per batch image (32 WGs x 384 threads), all f32
// ---------------------------------------------------------------------------
__device__ __forceinline__ float cbn_step(float* cur, float* red, int tid, int r, int c,
                                          bool act, const float* kk, float cb, float gm,
                                          float bt, int w, int l) {
  float y = 0.f;
  if (act) {
#pragma unroll
    for (int dr = -1; dr <= 1; dr++) {
#pragma unroll
      for (int dc = -1; dc <= 1; dc++) {
        int rr = r + dr, cc = c + dc;
        if (rr >= 0 && rr < 19 && cc >= 0 && cc < 19)
          y += cur[rr * 19 + cc] * kk[(dr + 1) * 3 + (dc + 1)];
      }
    }
    y += cb;
  }
  float s = act ? y : 0.f;
  float s2 = act ? y * y : 0.f;
#pragma unroll
  for (int o = 32; o >= 1; o >>= 1) {
    s += __shfl_xor(s, o);
    s2 += __shfl_xor(s2, o);
  }
  if (l == 0) { red[w] = s; red[8 + w] = s2; }
  __syncthreads();
  if (tid == 0) {
    float sa = 0.f, sb = 0.f;
    for (int i = 0; i < 6; i++) { sa += red[i]; sb += red[8 + i]; }
    float m = sa * (1.f / 361.f);
    float v = sb * (1.f / 361.f) - m * m;
    red[14] = m;
    red[15] = rsqrtf(v + 1e-5f) * gm;
  }
  __syncthreads();
  float m = red[14], sc = red[15];
  return act ? ((y - m) * sc + bt) : 0.f;
}

__global__ __launch_bounds__(384) void k1_tower(
    const float* __restrict__ board, const float* __restrict__ convk,
    const float* __restrict__ convb, const float* __restrict__ gma,
    const float* __restrict__ bta, const float* __restrict__ linW,
    const float* __restrict__ linb, const float* __restrict__ Wih,
    float* __restrict__ Z0) {
  const int b = blockIdx.x, tid = threadIdx.x;
  const int w = tid >> 6, l = tid & 63;
  __shared__ __align__(16) float cur[361];
  __shared__ __align__(16) float red[16];
  __shared__ __align__(16) float fs[256];
  const bool act = tid < 361;
  const int r = tid / 19, c = tid - r * 19;
  float kk[9];
#pragma unroll
  for (int i = 0; i < 9; i++) kk[i] = convk[i];
  const float cb = convb[0], gm = gma[0], bt = bta[0];
  if (act) cur[tid] = board[b * 361 + tid];
  __syncthreads();

  float v = cbn_step(cur, red, tid, r, c, act, kk, cb, gm, bt, w, l);
  float d2v = fmaxf(v, 0.f);
  if (act) cur[tid] = d2v;
  __syncthreads();
  for (int it = 0; it < 3; it++) {
    v = cbn_step(cur, red, tid, r, c, act, kk, cb, gm, bt, w, l);
    if (act) cur[tid] = fmaxf(v, 0.f);
    __syncthreads();
    v = cbn_step(cur, red, tid, r, c, act, kk, cb, gm, bt, w, l);
    float nv = fmaxf(v + d2v, 0.f);
    if (act) cur[tid] = nv;
    d2v = nv;
    __syncthreads();
  }
  v = cbn_step(cur, red, tid, r, c, act, kk, cb, gm, bt, w, l);
  if (act) cur[tid] = fmaxf(v, 0.f);
  __syncthreads();

  // feat[d] = sum_p d1[p]*lin_W[d][p] + lin_b[d]
  if (tid < 256) {
    float f = linb[tid];
    const float* wr = linW + tid * 361;
    for (int p = 0; p < 361; p++) f += cur[p] * wr[p];
    fs[tid] = f;
  }
  __syncthreads();
  // Z0[b][r] = sum_k feat[k]*Wih[r][k]   (full f32)
  for (int rr = tid; rr < 1024; rr += 384) {
    const float* wr = Wih + rr * 256;
    float z = 0.f;
#pragma unroll 4
    for (int k2 = 0; k2 < 256; k2++) z += fs[k2] * wr[k2];
    Z0[b * 1024 + rr] = z;
  }
}

// ---------------------------------------------------------------------------
// GEMM: C[m][n] = sum_k A[m][k]*W[n][k] (+bias), K=256 fixed, A/W bf16.
// DEC=1: out f32 with row permutation m=(t*32+b) -> out[(b*719+t)*6000+n], +bias
// DEC=0: out f32 plain, row stride 1024 (XWvocab = embed_bf @ Wih_bf.T)
// ---------------------------------------------------------------------------
template <int DEC>
__global__ __launch_bounds__(256) void gemm_k256(
    const u16* __restrict__ A, const u16* __restrict__ W,
    const float* __restrict__ bias, float* __restrict__ outp, int M, int N) {
  __shared__ __align__(16) u16 As[128 * 72];
  __shared__ __align__(16) u16 Ws[128 * 72];
  const int tid = threadIdx.x;
  const int w = tid >> 6, l = tid & 63, ln = l & 15, q = l >> 4;
  const int wm = (w >> 1) * 64, wn = (w & 1) * 64;
  const int m0 = blockIdx.y * 128, n0 = blockIdx.x * 128;
  f32x4 zero4 = {0.f, 0.f, 0.f, 0.f};
  f32x4 acc[4][4];
#pragma unroll
  for (int i = 0; i < 4; i++)
#pragma unroll
    for (int j = 0; j < 4; j++) acc[i][j] = zero4;

  for (int kb = 0; kb < 4; kb++) {
    if (kb) __syncthreads();
#pragma unroll
    for (int i = 0; i < 4; i++) {
      int ch = tid + i * 256;
      int row = ch >> 3, cj = ch & 7;
      int ga = m0 + row; if (ga > M - 1) ga = M - 1;
      int gw = n0 + row; if (gw > N - 1) gw = N - 1;
      *(u32x4*)&As[row * 72 + cj * 8] = *(const u32x4*)(A + (size_t)ga * 256 + kb * 64 + cj * 8);
      *(u32x4*)&Ws[row * 72 + cj * 8] = *(const u32x4*)(W + (size_t)gw * 256 + kb * 64 + cj * 8);
    }
    __syncthreads();
#pragma unroll
    for (int kk = 0; kk < 2; kk++) {
      bf16x8 af[4], wf[4];
#pragma unroll
      for (int mt = 0; mt < 4; mt++) af[mt] = ld8(&As[(wm + mt * 16 + ln) * 72 + kk * 32 + q * 8]);
#pragma unroll
      for (int nt = 0; nt < 4; nt++) wf[nt] = ld8(&Ws[(wn + nt * 16 + ln) * 72 + kk * 32 + q * 8]);
#pragma unroll
      for (int mt = 0; mt < 4; mt++)
#pragma unroll
        for (int nt = 0; nt < 4; nt++) acc[mt][nt] = MFMA16(af[mt], wf[nt], acc[mt][nt]);
    }
  }
  // epilogue: C/D layout col(n)=lane&15, row(m)=q*4+rr
#pragma unroll
  for (int mt = 0; mt < 4; mt++) {
#pragma unroll
    for (int nt = 0; nt < 4; nt++) {
      int n = n0 + wn + nt * 16 + ln;
#pragma unroll
      for (int rr = 0; rr < 4; rr++) {
        int m = m0 + wm + mt * 16 + q * 4 + rr;
        float vv = acc[mt][nt][rr];
        if (m < M && n < N) {
          if (DEC) {
            vv += bias[n];
            int tt = m >> 5, bb = m & 31;
            outp[((size_t)bb * 719 + tt) * 6000 + n] = vv;
          } else {
            outp[(size_t)m * 1024 + n] = vv;
          }
        }
      }
    }
  }
}

// ---------------------------------------------------------------------------
// K3: LSTM recurrence. 8 WGs x 512 threads. WG wg owns h-cols [wg*32, wg*32+32)
// => 128 gate rows of Whh (bf16 MFMA A-fragments, persistent in VGPRs).
// h exchanged per step via H[t][b][d] (t-major bf16, fresh addresses every
// step). Sync: 64 per-(wg,wave) flag words (16-B slots, no shared line, no
// RMW). Producer wave: relaxed agent stores of its 4-batch h piece, then
// lane0 release-stores its flag (per-wave vmcnt covers exactly those stores).
// Consumer: every wave polls all 64 flags in parallel (one per lane, acquire
// = L2-inv so the subsequent relaxed agent H loads are coherent). No
// threadfence, no counter ping-pong, 2 barriers/step.
// ---------------------------------------------------------------------------
__global__ __launch_bounds__(512) void rnn719(
    const float* __restrict__ Whh, const int* __restrict__ cmt,
    const float* __restrict__ Z0, const float* __restrict__ XW,
    const float* __restrict__ bih, const float* __restrict__ bhh,
    u16* __restrict__ H, u32* __restrict__ flags) {
  const int tid = threadIdx.x, wg = blockIdx.x;
  const int j0 = wg * 32;
  const int w = tid >> 6, l = tid & 63, ln = l & 15, q = l >> 4;
  const int ntile = w & 1, mpair = w >> 1;
  __shared__ __align__(16) u16 hs[32 * 264];     // h_{t-1}, padded stride
  __shared__ __align__(16) float gbuf[128 * 33]; // Whh@h partial gates

  // persistent A-fragments: A[m=lane&15][k=q*8+j]
  bf16x8 afr[2][8];
#pragma unroll
  for (int mt = 0; mt < 2; mt++) {
    int mu = (mpair * 2 + mt) * 16 + ln;   // local gate-row index [0,128)
    int gate = mu >> 5, jj = mu & 31;
    const float* rp = Whh + (size_t)(gate * 256 + j0 + jj) * 256;
#pragma unroll
    for (int kk = 0; kk < 8; kk++) {
      union { u16 t[8]; bf16x8 v; } u;
#pragma unroll
      for (int e = 0; e < 8; e++) u.t[e] = f2bf(rp[kk * 32 + q * 8 + e]);
      afr[mt][kk] = u.v;
    }
  }

  // gate-phase mapping: thread -> (batch gb, j-pair jp); wave w covers
  // batches 4w..4w+3 -> wave-level flag granularity is exact.
  const int gb = tid >> 4;
  const int jp = (tid & 15) * 2;
  float bs[4][2];
#pragma unroll
  for (int gt = 0; gt < 4; gt++) {
    bs[gt][0] = bih[gt * 256 + j0 + jp] + bhh[gt * 256 + j0 + jp];
    bs[gt][1] = bih[gt * 256 + j0 + jp + 1] + bhh[gt * 256 + j0 + jp + 1];
  }
  float c2[2] = {0.f, 0.f};

  u32* const myflag = flags + (size_t)(wg * 8 + w) * 4;  // 16-B slots
  const u32* const pollflag = flags + (size_t)l * 4;      // lane l polls flag l

  for (int t = 0; t < 719; t++) {
    // x-part gather: Z0 at t=0, XWvocab[token] else, 0 if masked
    // (issued before the flag wait so the latency hides under the poll)
    float zv[4][2];
    const float* base = nullptr;
    if (t == 0) {
      base = Z0 + gb * 1024;
    } else {
      int idx = cmt[gb * 719 + t];
      if (idx >= 0) base = XW + (size_t)idx * 1024;
    }
    if (base) {
#pragma unroll
      for (int gt = 0; gt < 4; gt++) {
        f32x2 v2 = *(const f32x2*)(base + gt * 256 + j0 + jp);
        zv[gt][0] = v2[0]; zv[gt][1] = v2[1];
      }
    } else {
#pragma unroll
      for (int gt = 0; gt < 4; gt++) { zv[gt][0] = 0.f; zv[gt][1] = 0.f; }
    }

    if (t > 0) {
      // wait: all 64 producer-wave pieces of h_{t-1} published.
      // one flag per lane; lanes exit independently, wave exits at max().
      {
        int guard = 0;
        while (__hip_atomic_load(pollflag, __ATOMIC_ACQUIRE,
                                 __HIP_MEMORY_SCOPE_AGENT) < (u32)t) {
          if (++guard > (1 << 22)) break;  // safety valve vs hang
        }
      }
      // stage h_{t-1} (32x256 bf16) into LDS
      u64* hp = (u64*)(H + (size_t)(t - 1) * 8192);
#pragma unroll
      for (int i = 0; i < 4; i++) {
        int ch = tid + i * 512;
        int row = ch >> 6, c6 = ch & 63;
        u64 v = __hip_atomic_load(hp + ch, __ATOMIC_RELAXED, __HIP_MEMORY_SCOPE_AGENT);
        *(u64*)&hs[row * 264 + c6 * 4] = v;
      }
      __syncthreads();
      // D[m=gate-row][n=batch] = Whh_slice @ h
      f32x4 a0 = {0.f, 0.f, 0.f, 0.f}, a1 = a0;
#pragma unroll
      for (int kk = 0; kk < 8; kk++) {
        bf16x8 bfr = ld8(&hs[(ntile * 16 + ln) * 264 + kk * 32 + q * 8]);
        a0 = MFMA16(afr[0][kk], bfr, a0);
        a1 = MFMA16(afr[1][kk], bfr, a1);
      }
#pragma unroll
      for (int rr = 0; rr < 4; rr++) {
        gbuf[((mpair * 2 + 0) * 16 + q * 4 + rr) * 33 + ntile * 16 + ln] = a0[rr];
        gbuf[((mpair * 2 + 1) * 16 + q * 4 + rr) * 33 + ntile * 16 + ln] = a1[rr];
      }
      __syncthreads();
    }

    // gates, c/h update for this WG's 32 j-columns
    u32 hpk = 0;
#pragma unroll
    for (int pj = 0; pj < 2; pj++) {
      int j = jp + pj;
      float gi = zv[0][pj] + bs[0][pj];
      float gf = zv[1][pj] + bs[1][pj];
      float gg = zv[2][pj] + bs[2][pj];
      float go = zv[3][pj] + bs[3][pj];
      if (t > 0) {
        gi += gbuf[(j) * 33 + gb];
        gf += gbuf[(32 + j) * 33 + gb];
        gg += gbuf[(64 + j) * 33 + gb];
        go += gbuf[(96 + j) * 33 + gb];
      }
      float ii = sigm(gi);
      float ff = sigm(gf);
      float g2 = tanh_f(gg);
      float oo = sigm(go);
      float cc = ff * c2[pj] + ii * g2;
      c2[pj] = cc;
      float hh = oo * tanh_f(cc);
      hpk |= ((u32)f2bf(hh)) << (16 * pj);
    }
    // publish h_t piece (device-visible), then per-wave release flag.
    __hip_atomic_store((u32*)(H + (size_t)t * 8192 + gb * 256 + j0 + jp), hpk,
                       __ATOMIC_RELAXED, __HIP_MEMORY_SCOPE_AGENT);
    if (l == 0)
      __hip_atomic_store(myflag, (u32)(t + 1), __ATOMIC_RELEASE,
                         __HIP_MEMORY_SCOPE_AGENT);
  }
}

// ---------------------------------------------------------------------------
extern "C" void kernel_launch(void* const* d_in, const int* in_sizes, int n_in,
                              void* d_out, int out_size, void* d_ws, size_t ws_size,
                              hipStream_t stream) {
  const float* board = (const float*)d_in[0];
  const int*   cmt   = (const int*)d_in[1];
  const float* convk = (const float*)d_in[2];
  const float* convb = (const float*)d_in[3];
  const float* gma   = (const float*)d_in[4];
  const float* bta   = (const float*)d_in[5];
  const float* embed = (const float*)d_in[6];
  const float* linW  = (const float*)d_in[7];
  const float* linb  = (const float*)d_in[8];
  const float* Wih   = (const float*)d_in[9];
  const float* Whh   = (const float*)d_in[10];
  const float* bihp  = (const float*)d_in[11];
  const float* bhhp  = (const float*)d_in[12];
  const float* decW  = (const float*)d_in[13];
  const float* decb  = (const float*)d_in[14];

  char* ws = (char*)d_ws;
  u32*  flags   = (u32*)ws;                          // 64 x 16B = 1024
  float* Z0     = (float*)(ws + 1024);               // 32*1024 f32     -> 132,096
  float* XW     = (float*)(ws + 132096);             // 6000*1024 f32   -> 24,708,096
  u16*  H       = (u16*)(ws + 24708096);             // 719*32*256 bf16 -> 36,488,192
  u16*  embedB  = (u16*)(ws + 36488192);             // 6000*256 bf16   -> 39,560,192
  u16*  WihB    = (u16*)(ws + 39560192);             // 1024*256 bf16   -> 40,084,480
  u16*  decWB   = (u16*)(ws + 40084480);             // 6000*256 bf16   -> 43,156,480

  hipMemsetAsync(flags, 0, 1024, stream);  // flags must be 0 every launch
  hipLaunchKernelGGL(castbf, dim3(1500), dim3(256), 0, stream, embed, embedB, 384000);
  hipLaunchKernelGGL(castbf, dim3(256),  dim3(256), 0, stream, Wih,   WihB,   65536);
  hipLaunchKernelGGL(castbf, dim3(1500), dim3(256), 0, stream, decW,  decWB,  384000);
  hipLaunchKernelGGL(k1_tower, dim3(32), dim3(384), 0, stream,
                     board, convk, convb, gma, bta, linW, linb, Wih, Z0);
  hipLaunchKernelGGL((gemm_k256<0>), dim3(8, 47), dim3(256), 0, stream,
                     embedB, WihB, (const float*)nullptr, XW, 6000, 1024);
  hipLaunchKernelGGL(rnn719, dim3(8), dim3(512), 0, stream,
                     Whh, cmt, Z0, XW, bihp, bhhp, H, flags);
  hipLaunchKernelGGL((gemm_k256<1>), dim3(47, 180), dim3(256), 0, stream,
                     H, decWB, decb, (float*)d_out, 23008, 6000);
  (void)in_sizes; (void)n_in; (void)out_size; (void)ws_size;
}

// Round 2
// 3623.847 us; speedup vs baseline: 1.2673x; 1.2673x over previous
//
#include <hip/hip_runtime.h>
#include <hip/hip_bf16.h>
#include <stdint.h>

typedef unsigned short u16;
typedef unsigned int u32;
typedef unsigned long long u64;
typedef float f32x4 __attribute__((ext_vector_type(4)));
typedef float f32x2 __attribute__((ext_vector_type(2)));
typedef u32 u32x4 __attribute__((ext_vector_type(4)));
typedef __bf16 bf16x8 __attribute__((ext_vector_type(8)));

#define MFMA16(A, B, C) __builtin_amdgcn_mfma_f32_16x16x32_bf16((A), (B), (C), 0, 0, 0)

__device__ __forceinline__ u16 f2bf(float f) {
  u32 u = __float_as_uint(f);
  u32 r = (u + 0x7fffu + ((u >> 16) & 1u)) >> 16;
  return (u16)r;
}
__device__ __forceinline__ bf16x8 ld8(const u16* p) {
  return __builtin_bit_cast(bf16x8, *(const u32x4*)p);
}
// fast sigmoid/tanh via v_exp; safe for all finite inputs
__device__ __forceinline__ float sigm(float x) { return 1.f / (1.f + __expf(-x)); }
__device__ __forceinline__ float tanh_f(float x) {
  float a = fabsf(x);
  float e = __expf(-2.f * a);          // e in (0,1], never overflows
  float r = (1.f - e) / (1.f + e);
  return copysignf(r, x);
}

// ---------------------------------------------------------------------------
// cast f32 -> bf16 (RNE), 4 elems/thread
// ---------------------------------------------------------------------------
__global__ __launch_bounds__(256) void castbf(const float* __restrict__ s,
                                              u16* __restrict__ d, int n4) {
  int i = blockIdx.x * 256 + threadIdx.x;
  if (i >= n4) return;
  f32x4 v = *(const f32x4*)(s + (size_t)i * 4);
  union { u16 t[4]; u64 v; } u;
#pragma unroll
  for (int e = 0; e < 4; e++) u.t[e] = f2bf(v[e]);
  *(u64*)(d + (size_t)i * 4) = u.v;
}

// ---------------------------------------------------------------------------
// K1: conv tower (8x conv+instance-norm, residuals) + feat + Z0 = feat@Wih.T
// one workgroup per batch image (32 WGs x 384 threads), all f32
// ---------------------------------------------------------------------------
__device__ __forceinline__ float cbn_step(float* cur, float* red, int tid, int r, int c,
                                          bool act, const float* kk, float cb, float gm,
                                          float bt, int w, int l) {
  float y = 0.f;
  if (act) {
#pragma unroll
    for (int dr = -1; dr <= 1; dr++) {
#pragma unroll
      for (int dc = -1; dc <= 1; dc++) {
        int rr = r + dr, cc = c + dc;
        if (rr >= 0 && rr < 19 && cc >= 0 && cc < 19)
          y += cur[rr * 19 + cc] * kk[(dr + 1) * 3 + (dc + 1)];
      }
    }
    y += cb;
  }
  float s = act ? y : 0.f;
  float s2 = act ? y * y : 0.f;
#pragma unroll
  for (int o = 32; o >= 1; o >>= 1) {
    s += __shfl_xor(s, o);
    s2 += __shfl_xor(s2, o);
  }
  if (l == 0) { red[w] = s; red[8 + w] = s2; }
  __syncthreads();
  if (tid == 0) {
    float sa = 0.f, sb = 0.f;
    for (int i = 0; i < 6; i++) { sa += red[i]; sb += red[8 + i]; }
    float m = sa * (1.f / 361.f);
    float v = sb * (1.f / 361.f) - m * m;
    red[14] = m;
    red[15] = rsqrtf(v + 1e-5f) * gm;
  }
  __syncthreads();
  float m = red[14], sc = red[15];
  return act ? ((y - m) * sc + bt) : 0.f;
}

__global__ __launch_bounds__(384) void k1_tower(
    const float* __restrict__ board, const float* __restrict__ convk,
    const float* __restrict__ convb, const float* __restrict__ gma,
    const float* __restrict__ bta, const float* __restrict__ linW,
    const float* __restrict__ linb, const float* __restrict__ Wih,
    float* __restrict__ Z0) {
  const int b = blockIdx.x, tid = threadIdx.x;
  const int w = tid >> 6, l = tid & 63;
  __shared__ __align__(16) float cur[361];
  __shared__ __align__(16) float red[16];
  __shared__ __align__(16) float fs[256];
  const bool act = tid < 361;
  const int r = tid / 19, c = tid - r * 19;
  float kk[9];
#pragma unroll
  for (int i = 0; i < 9; i++) kk[i] = convk[i];
  const float cb = convb[0], gm = gma[0], bt = bta[0];
  if (act) cur[tid] = board[b * 361 + tid];
  __syncthreads();

  float v = cbn_step(cur, red, tid, r, c, act, kk, cb, gm, bt, w, l);
  float d2v = fmaxf(v, 0.f);
  if (act) cur[tid] = d2v;
  __syncthreads();
  for (int it = 0; it < 3; it++) {
    v = cbn_step(cur, red, tid, r, c, act, kk, cb, gm, bt, w, l);
    if (act) cur[tid] = fmaxf(v, 0.f);
    __syncthreads();
    v = cbn_step(cur, red, tid, r, c, act, kk, cb, gm, bt, w, l);
    float nv = fmaxf(v + d2v, 0.f);
    if (act) cur[tid] = nv;
    d2v = nv;
    __syncthreads();
  }
  v = cbn_step(cur, red, tid, r, c, act, kk, cb, gm, bt, w, l);
  if (act) cur[tid] = fmaxf(v, 0.f);
  __syncthreads();

  // feat[d] = sum_p d1[p]*lin_W[d][p] + lin_b[d]
  if (tid < 256) {
    float f = linb[tid];
    const float* wr = linW + tid * 361;
    for (int p = 0; p < 361; p++) f += cur[p] * wr[p];
    fs[tid] = f;
  }
  __syncthreads();
  // Z0[b][r] = sum_k feat[k]*Wih[r][k]   (full f32)
  for (int rr = tid; rr < 1024; rr += 384) {
    const float* wr = Wih + rr * 256;
    float z = 0.f;
#pragma unroll 4
    for (int k2 = 0; k2 < 256; k2++) z += fs[k2] * wr[k2];
    Z0[b * 1024 + rr] = z;
  }
}

// ---------------------------------------------------------------------------
// GEMM: C[m][n] = sum_k A[m][k]*W[n][k] (+bias), K=256 fixed, A/W bf16.
// DEC=1: out f32 with row permutation m=(t*32+b) -> out[(b*719+t)*6000+n], +bias
// DEC=0: out f32 plain, row stride 1024 (XWvocab = embed_bf @ Wih_bf.T)
// ---------------------------------------------------------------------------
template <int DEC>
__global__ __launch_bounds__(256) void gemm_k256(
    const u16* __restrict__ A, const u16* __restrict__ W,
    const float* __restrict__ bias, float* __restrict__ outp, int M, int N) {
  __shared__ __align__(16) u16 As[128 * 72];
  __shared__ __align__(16) u16 Ws[128 * 72];
  const int tid = threadIdx.x;
  const int w = tid >> 6, l = tid & 63, ln = l & 15, q = l >> 4;
  const int wm = (w >> 1) * 64, wn = (w & 1) * 64;
  const int m0 = blockIdx.y * 128, n0 = blockIdx.x * 128;
  f32x4 zero4 = {0.f, 0.f, 0.f, 0.f};
  f32x4 acc[4][4];
#pragma unroll
  for (int i = 0; i < 4; i++)
#pragma unroll
    for (int j = 0; j < 4; j++) acc[i][j] = zero4;

  for (int kb = 0; kb < 4; kb++) {
    if (kb) __syncthreads();
#pragma unroll
    for (int i = 0; i < 4; i++) {
      int ch = tid + i * 256;
      int row = ch >> 3, cj = ch & 7;
      int ga = m0 + row; if (ga > M - 1) ga = M - 1;
      int gw = n0 + row; if (gw > N - 1) gw = N - 1;
      *(u32x4*)&As[row * 72 + cj * 8] = *(const u32x4*)(A + (size_t)ga * 256 + kb * 64 + cj * 8);
      *(u32x4*)&Ws[row * 72 + cj * 8] = *(const u32x4*)(W + (size_t)gw * 256 + kb * 64 + cj * 8);
    }
    __syncthreads();
#pragma unroll
    for (int kk = 0; kk < 2; kk++) {
      bf16x8 af[4], wf[4];
#pragma unroll
      for (int mt = 0; mt < 4; mt++) af[mt] = ld8(&As[(wm + mt * 16 + ln) * 72 + kk * 32 + q * 8]);
#pragma unroll
      for (int nt = 0; nt < 4; nt++) wf[nt] = ld8(&Ws[(wn + nt * 16 + ln) * 72 + kk * 32 + q * 8]);
#pragma unroll
      for (int mt = 0; mt < 4; mt++)
#pragma unroll
        for (int nt = 0; nt < 4; nt++) acc[mt][nt] = MFMA16(af[mt], wf[nt], acc[mt][nt]);
    }
  }
  // epilogue: C/D layout col(n)=lane&15, row(m)=q*4+rr
#pragma unroll
  for (int mt = 0; mt < 4; mt++) {
#pragma unroll
    for (int nt = 0; nt < 4; nt++) {
      int n = n0 + wn + nt * 16 + ln;
#pragma unroll
      for (int rr = 0; rr < 4; rr++) {
        int m = m0 + wm + mt * 16 + q * 4 + rr;
        float vv = acc[mt][nt][rr];
        if (m < M && n < N) {
          if (DEC) {
            vv += bias[n];
            int tt = m >> 5, bb = m & 31;
            outp[((size_t)bb * 719 + tt) * 6000 + n] = vv;
          } else {
            outp[(size_t)m * 1024 + n] = vv;
          }
        }
      }
    }
  }
}

// ---------------------------------------------------------------------------
// K3: LSTM recurrence. 8 WGs x 512 threads. WG wg owns h-cols [wg*32, wg*32+32)
// => 128 gate rows of Whh (bf16 MFMA A-fragments, persistent in VGPRs).
// h exchanged per step via H[t][b][d] (t-major bf16, fresh addresses every
// step) + 64 per-(wg,wave) flag words (16-B slots).
// ALL atomics RELAXED (agent scope -> sc1 accesses bypass L1/L2, so they can
// never see stale cached data; no acquire/release fences -> NO buffer_inv /
// buffer_wbl2 cache-maintenance storms, L2 stays warm for the XW gather).
// The single true ordering need -- h stores reach the coherence point before
// the flag does -- is provided by an explicit `s_waitcnt vmcnt(0)` between
// the h publish and the flag publish.
// ---------------------------------------------------------------------------
__global__ __launch_bounds__(512) void rnn719(
    const float* __restrict__ Whh, const int* __restrict__ cmt,
    const float* __restrict__ Z0, const float* __restrict__ XW,
    const float* __restrict__ bih, const float* __restrict__ bhh,
    u16* __restrict__ H, u32* __restrict__ flags) {
  const int tid = threadIdx.x, wg = blockIdx.x;
  const int j0 = wg * 32;
  const int w = tid >> 6, l = tid & 63, ln = l & 15, q = l >> 4;
  const int ntile = w & 1, mpair = w >> 1;
  __shared__ __align__(16) u16 hs[32 * 264];     // h_{t-1}, padded stride
  __shared__ __align__(16) float gbuf[128 * 33]; // Whh@h partial gates

  // persistent A-fragments: A[m=lane&15][k=q*8+j]
  bf16x8 afr[2][8];
#pragma unroll
  for (int mt = 0; mt < 2; mt++) {
    int mu = (mpair * 2 + mt) * 16 + ln;   // local gate-row index [0,128)
    int gate = mu >> 5, jj = mu & 31;
    const float* rp = Whh + (size_t)(gate * 256 + j0 + jj) * 256;
#pragma unroll
    for (int kk = 0; kk < 8; kk++) {
      union { u16 t[8]; bf16x8 v; } u;
#pragma unroll
      for (int e = 0; e < 8; e++) u.t[e] = f2bf(rp[kk * 32 + q * 8 + e]);
      afr[mt][kk] = u.v;
    }
  }

  // gate-phase mapping: thread -> (batch gb, j-pair jp); wave w covers
  // batches 4w..4w+3 -> wave-level flag granularity is exact.
  const int gb = tid >> 4;
  const int jp = (tid & 15) * 2;
  float bs[4][2];
#pragma unroll
  for (int gt = 0; gt < 4; gt++) {
    bs[gt][0] = bih[gt * 256 + j0 + jp] + bhh[gt * 256 + j0 + jp];
    bs[gt][1] = bih[gt * 256 + j0 + jp + 1] + bhh[gt * 256 + j0 + jp + 1];
  }
  float c2[2] = {0.f, 0.f};

  u32* const myflag = flags + (size_t)(wg * 8 + w) * 4;  // 16-B slots
  const u32* const pollflag = flags + (size_t)l * 4;      // lane l polls flag l

  for (int t = 0; t < 719; t++) {
    // x-part gather: Z0 at t=0, XWvocab[token] else, 0 if masked
    // (issued before the flag wait so the latency hides under the poll)
    float zv[4][2];
    const float* base = nullptr;
    if (t == 0) {
      base = Z0 + gb * 1024;
    } else {
      int idx = cmt[gb * 719 + t];
      if (idx >= 0) base = XW + (size_t)idx * 1024;
    }
    if (base) {
#pragma unroll
      for (int gt = 0; gt < 4; gt++) {
        f32x2 v2 = *(const f32x2*)(base + gt * 256 + j0 + jp);
        zv[gt][0] = v2[0]; zv[gt][1] = v2[1];
      }
    } else {
#pragma unroll
      for (int gt = 0; gt < 4; gt++) { zv[gt][0] = 0.f; zv[gt][1] = 0.f; }
    }

    if (t > 0) {
      // wait: all 64 producer-wave pieces of h_{t-1} published.
      // one flag per lane; RELAXED sc1 load -> no cache-inv per iteration.
      {
        int guard = 0;
        while (__hip_atomic_load(pollflag, __ATOMIC_RELAXED,
                                 __HIP_MEMORY_SCOPE_AGENT) < (u32)t) {
          if (++guard > (1 << 22)) break;  // safety valve vs hang
        }
      }
      // stage h_{t-1} (32x256 bf16) into LDS; sc1 loads read the coherence
      // point directly, no fence needed.
      u64* hp = (u64*)(H + (size_t)(t - 1) * 8192);
#pragma unroll
      for (int i = 0; i < 4; i++) {
        int ch = tid + i * 512;
        int row = ch >> 6, c6 = ch & 63;
        u64 v = __hip_atomic_load(hp + ch, __ATOMIC_RELAXED, __HIP_MEMORY_SCOPE_AGENT);
        *(u64*)&hs[row * 264 + c6 * 4] = v;
      }
      __syncthreads();
      // D[m=gate-row][n=batch] = Whh_slice @ h
      f32x4 a0 = {0.f, 0.f, 0.f, 0.f}, a1 = a0;
#pragma unroll
      for (int kk = 0; kk < 8; kk++) {
        bf16x8 bfr = ld8(&hs[(ntile * 16 + ln) * 264 + kk * 32 + q * 8]);
        a0 = MFMA16(afr[0][kk], bfr, a0);
        a1 = MFMA16(afr[1][kk], bfr, a1);
      }
#pragma unroll
      for (int rr = 0; rr < 4; rr++) {
        gbuf[((mpair * 2 + 0) * 16 + q * 4 + rr) * 33 + ntile * 16 + ln] = a0[rr];
        gbuf[((mpair * 2 + 1) * 16 + q * 4 + rr) * 33 + ntile * 16 + ln] = a1[rr];
      }
      __syncthreads();
    }

    // gates, c/h update for this WG's 32 j-columns
    u32 hpk = 0;
#pragma unroll
    for (int pj = 0; pj < 2; pj++) {
      int j = jp + pj;
      float gi = zv[0][pj] + bs[0][pj];
      float gf = zv[1][pj] + bs[1][pj];
      float gg = zv[2][pj] + bs[2][pj];
      float go = zv[3][pj] + bs[3][pj];
      if (t > 0) {
        gi += gbuf[(j) * 33 + gb];
        gf += gbuf[(32 + j) * 33 + gb];
        gg += gbuf[(64 + j) * 33 + gb];
        go += gbuf[(96 + j) * 33 + gb];
      }
      float ii = sigm(gi);
      float ff = sigm(gf);
      float g2 = tanh_f(gg);
      float oo = sigm(go);
      float cc = ff * c2[pj] + ii * g2;
      c2[pj] = cc;
      float hh = oo * tanh_f(cc);
      hpk |= ((u32)f2bf(hh)) << (16 * pj);
    }
    // publish h_t piece (sc1, write-through past L2), then per-wave flag.
    __hip_atomic_store((u32*)(H + (size_t)t * 8192 + gb * 256 + j0 + jp), hpk,
                       __ATOMIC_RELAXED, __HIP_MEMORY_SCOPE_AGENT);
    // order: h stores must reach the coherence point before the flag store.
    asm volatile("s_waitcnt vmcnt(0)" ::: "memory");
    if (l == 0)
      __hip_atomic_store(myflag, (u32)(t + 1), __ATOMIC_RELAXED,
                         __HIP_MEMORY_SCOPE_AGENT);
  }
}

// ---------------------------------------------------------------------------
extern "C" void kernel_launch(void* const* d_in, const int* in_sizes, int n_in,
                              void* d_out, int out_size, void* d_ws, size_t ws_size,
                              hipStream_t stream) {
  const float* board = (const float*)d_in[0];
  const int*   cmt   = (const int*)d_in[1];
  const float* convk = (const float*)d_in[2];
  const float* convb = (const float*)d_in[3];
  const float* gma   = (const float*)d_in[4];
  const float* bta   = (const float*)d_in[5];
  const float* embed = (const float*)d_in[6];
  const float* linW  = (const float*)d_in[7];
  const float* linb  = (const float*)d_in[8];
  const float* Wih   = (const float*)d_in[9];
  const float* Whh   = (const float*)d_in[10];
  const float* bihp  = (const float*)d_in[11];
  const float* bhhp  = (const float*)d_in[12];
  const float* decW  = (const float*)d_in[13];
  const float* decb  = (const float*)d_in[14];

  char* ws = (char*)d_ws;
  u32*  flags   = (u32*)ws;                          // 64 x 16B = 1024
  float* Z0     = (float*)(ws + 1024);               // 32*1024 f32     -> 132,096
  float* XW     = (float*)(ws + 132096);             // 6000*1024 f32   -> 24,708,096
  u16*  H       = (u16*)(ws + 24708096);             // 719*32*256 bf16 -> 36,488,192
  u16*  embedB  = (u16*)(ws + 36488192);             // 6000*256 bf16   -> 39,560,192
  u16*  WihB    = (u16*)(ws + 39560192);             // 1024*256 bf16   -> 40,084,480
  u16*  decWB   = (u16*)(ws + 40084480);             // 6000*256 bf16   -> 43,156,480

  hipMemsetAsync(flags, 0, 1024, stream);  // flags must be 0 every launch
  hipLaunchKernelGGL(castbf, dim3(1500), dim3(256), 0, stream, embed, embedB, 384000);
  hipLaunchKernelGGL(castbf, dim3(256),  dim3(256), 0, stream, Wih,   WihB,   65536);
  hipLaunchKernelGGL(castbf, dim3(1500), dim3(256), 0, stream, decW,  decWB,  384000);
  hipLaunchKernelGGL(k1_tower, dim3(32), dim3(384), 0, stream,
                     board, convk, convb, gma, bta, linW, linb, Wih, Z0);
  hipLaunchKernelGGL((gemm_k256<0>), dim3(8, 47), dim3(256), 0, stream,
                     embedB, WihB, (const float*)nullptr, XW, 6000, 1024);
  hipLaunchKernelGGL(rnn719, dim3(8), dim3(512), 0, stream,
                     Whh, cmt, Z0, XW, bihp, bhhp, H, flags);
  hipLaunchKernelGGL((gemm_k256<1>), dim3(47, 180), dim3(256), 0, stream,
                     H, decWB, decb, (float*)d_out, 23008, 6000);
  (void)in_sizes; (void)n_in; (void)out_size; (void)ws_size;
}

// Round 3
// 2716.715 us; speedup vs baseline: 1.6904x; 1.3339x over previous
//
#include <hip/hip_runtime.h>
#include <hip/hip_bf16.h>
#include <stdint.h>

typedef unsigned short u16;
typedef unsigned int u32;
typedef unsigned long long u64;
typedef float f32x4 __attribute__((ext_vector_type(4)));
typedef float f32x2 __attribute__((ext_vector_type(2)));
typedef u32 u32x4 __attribute__((ext_vector_type(4)));
typedef __bf16 bf16x8 __attribute__((ext_vector_type(8)));

#define MFMA16(A, B, C) __builtin_amdgcn_mfma_f32_16x16x32_bf16((A), (B), (C), 0, 0, 0)

__device__ __forceinline__ u16 f2bf(float f) {
  u32 u = __float_as_uint(f);
  u32 r = (u + 0x7fffu + ((u >> 16) & 1u)) >> 16;
  return (u16)r;
}
__device__ __forceinline__ bf16x8 ld8(const u16* p) {
  return __builtin_bit_cast(bf16x8, *(const u32x4*)p);
}
// fast sigmoid/tanh via v_exp; safe for all finite inputs
__device__ __forceinline__ float sigm(float x) { return 1.f / (1.f + __expf(-x)); }
__device__ __forceinline__ float tanh_f(float x) {
  float a = fabsf(x);
  float e = __expf(-2.f * a);          // e in (0,1], never overflows
  float r = (1.f - e) / (1.f + e);
  return copysignf(r, x);
}

// ---------------------------------------------------------------------------
// cast f32 -> bf16 (RNE), 4 elems/thread
// ---------------------------------------------------------------------------
__global__ __launch_bounds__(256) void castbf(const float* __restrict__ s,
                                              u16* __restrict__ d, int n4) {
  int i = blockIdx.x * 256 + threadIdx.x;
  if (i >= n4) return;
  f32x4 v = *(const f32x4*)(s + (size_t)i * 4);
  union { u16 t[4]; u64 v; } u;
#pragma unroll
  for (int e = 0; e < 4; e++) u.t[e] = f2bf(v[e]);
  *(u64*)(d + (size_t)i * 4) = u.v;
}

// ---------------------------------------------------------------------------
// K1: conv tower (8x conv+instance-norm, residuals) + feat + Z0 = feat@Wih.T
// one workgroup per batch image (32 WGs x 384 threads), all f32
// ---------------------------------------------------------------------------
__device__ __forceinline__ float cbn_step(float* cur, float* red, int tid, int r, int c,
                                          bool act, const float* kk, float cb, float gm,
                                          float bt, int w, int l) {
  float y = 0.f;
  if (act) {
#pragma unroll
    for (int dr = -1; dr <= 1; dr++) {
#pragma unroll
      for (int dc = -1; dc <= 1; dc++) {
        int rr = r + dr, cc = c + dc;
        if (rr >= 0 && rr < 19 && cc >= 0 && cc < 19)
          y += cur[rr * 19 + cc] * kk[(dr + 1) * 3 + (dc + 1)];
      }
    }
    y += cb;
  }
  float s = act ? y : 0.f;
  float s2 = act ? y * y : 0.f;
#pragma unroll
  for (int o = 32; o >= 1; o >>= 1) {
    s += __shfl_xor(s, o);
    s2 += __shfl_xor(s2, o);
  }
  if (l == 0) { red[w] = s; red[8 + w] = s2; }
  __syncthreads();
  if (tid == 0) {
    float sa = 0.f, sb = 0.f;
    for (int i = 0; i < 6; i++) { sa += red[i]; sb += red[8 + i]; }
    float m = sa * (1.f / 361.f);
    float v = sb * (1.f / 361.f) - m * m;
    red[14] = m;
    red[15] = rsqrtf(v + 1e-5f) * gm;
  }
  __syncthreads();
  float m = red[14], sc = red[15];
  return act ? ((y - m) * sc + bt) : 0.f;
}

__global__ __launch_bounds__(384) void k1_tower(
    const float* __restrict__ board, const float* __restrict__ convk,
    const float* __restrict__ convb, const float* __restrict__ gma,
    const float* __restrict__ bta, const float* __restrict__ linW,
    const float* __restrict__ linb, const float* __restrict__ Wih,
    float* __restrict__ Z0) {
  const int b = blockIdx.x, tid = threadIdx.x;
  const int w = tid >> 6, l = tid & 63;
  __shared__ __align__(16) float cur[361];
  __shared__ __align__(16) float red[16];
  __shared__ __align__(16) float fs[256];
  const bool act = tid < 361;
  const int r = tid / 19, c = tid - r * 19;
  float kk[9];
#pragma unroll
  for (int i = 0; i < 9; i++) kk[i] = convk[i];
  const float cb = convb[0], gm = gma[0], bt = bta[0];
  if (act) cur[tid] = board[b * 361 + tid];
  __syncthreads();

  float v = cbn_step(cur, red, tid, r, c, act, kk, cb, gm, bt, w, l);
  float d2v = fmaxf(v, 0.f);
  if (act) cur[tid] = d2v;
  __syncthreads();
  for (int it = 0; it < 3; it++) {
    v = cbn_step(cur, red, tid, r, c, act, kk, cb, gm, bt, w, l);
    if (act) cur[tid] = fmaxf(v, 0.f);
    __syncthreads();
    v = cbn_step(cur, red, tid, r, c, act, kk, cb, gm, bt, w, l);
    float nv = fmaxf(v + d2v, 0.f);
    if (act) cur[tid] = nv;
    d2v = nv;
    __syncthreads();
  }
  v = cbn_step(cur, red, tid, r, c, act, kk, cb, gm, bt, w, l);
  if (act) cur[tid] = fmaxf(v, 0.f);
  __syncthreads();

  // feat[d] = sum_p d1[p]*lin_W[d][p] + lin_b[d]
  if (tid < 256) {
    float f = linb[tid];
    const float* wr = linW + tid * 361;
    for (int p = 0; p < 361; p++) f += cur[p] * wr[p];
    fs[tid] = f;
  }
  __syncthreads();
  // Z0[b][r] = sum_k feat[k]*Wih[r][k]   (full f32)
  for (int rr = tid; rr < 1024; rr += 384) {
    const float* wr = Wih + rr * 256;
    float z = 0.f;
#pragma unroll 4
    for (int k2 = 0; k2 < 256; k2++) z += fs[k2] * wr[k2];
    Z0[b * 1024 + rr] = z;
  }
}

// ---------------------------------------------------------------------------
// GEMM: C[m][n] = sum_k A[m][k]*W[n][k] (+bias), K=256 fixed, W bf16.
// DEC=1: A is TAGGED u64 words (low32 = 2 bf16, high32 = step tag, stripped
//        here); out f32, row permutation m=(t*32+b) -> out[(b*719+t)*6000+n], +bias
// DEC=0: A plain bf16; out f32, row stride 1024 (XWvocab = embed_bf @ Wih_bf.T)
// ---------------------------------------------------------------------------
template <int DEC>
__global__ __launch_bounds__(256) void gemm_k256(
    const u16* __restrict__ A, const u16* __restrict__ W,
    const float* __restrict__ bias, float* __restrict__ outp, int M, int N) {
  __shared__ __align__(16) u16 As[128 * 72];
  __shared__ __align__(16) u16 Ws[128 * 72];
  const int tid = threadIdx.x;
  const int w = tid >> 6, l = tid & 63, ln = l & 15, q = l >> 4;
  const int wm = (w >> 1) * 64, wn = (w & 1) * 64;
  const int m0 = blockIdx.y * 128, n0 = blockIdx.x * 128;
  f32x4 zero4 = {0.f, 0.f, 0.f, 0.f};
  f32x4 acc[4][4];
#pragma unroll
  for (int i = 0; i < 4; i++)
#pragma unroll
    for (int j = 0; j < 4; j++) acc[i][j] = zero4;

  for (int kb = 0; kb < 4; kb++) {
    if (kb) __syncthreads();
#pragma unroll
    for (int i = 0; i < 4; i++) {
      int ch = tid + i * 256;
      int row = ch >> 3, cj = ch & 7;
      int ga = m0 + row; if (ga > M - 1) ga = M - 1;
      int gw = n0 + row; if (gw > N - 1) gw = N - 1;
      if (DEC) {
        // tagged A: 4 u64 words -> 8 bf16 (strip high32 tags)
        const u64* ap = (const u64*)A + (size_t)ga * 128 + kb * 32 + cj * 4;
        u64 w0 = ap[0], w1 = ap[1], w2 = ap[2], w3 = ap[3];
        u32 pk[4] = {(u32)w0, (u32)w1, (u32)w2, (u32)w3};
        *(u32x4*)&As[row * 72 + cj * 8] = *(const u32x4*)pk;
      } else {
        *(u32x4*)&As[row * 72 + cj * 8] = *(const u32x4*)(A + (size_t)ga * 256 + kb * 64 + cj * 8);
      }
      *(u32x4*)&Ws[row * 72 + cj * 8] = *(const u32x4*)(W + (size_t)gw * 256 + kb * 64 + cj * 8);
    }
    __syncthreads();
#pragma unroll
    for (int kk = 0; kk < 2; kk++) {
      bf16x8 af[4], wf[4];
#pragma unroll
      for (int mt = 0; mt < 4; mt++) af[mt] = ld8(&As[(wm + mt * 16 + ln) * 72 + kk * 32 + q * 8]);
#pragma unroll
      for (int nt = 0; nt < 4; nt++) wf[nt] = ld8(&Ws[(wn + nt * 16 + ln) * 72 + kk * 32 + q * 8]);
#pragma unroll
      for (int mt = 0; mt < 4; mt++)
#pragma unroll
        for (int nt = 0; nt < 4; nt++) acc[mt][nt] = MFMA16(af[mt], wf[nt], acc[mt][nt]);
    }
  }
  // epilogue: C/D layout col(n)=lane&15, row(m)=q*4+rr
#pragma unroll
  for (int mt = 0; mt < 4; mt++) {
#pragma unroll
    for (int nt = 0; nt < 4; nt++) {
      int n = n0 + wn + nt * 16 + ln;
#pragma unroll
      for (int rr = 0; rr < 4; rr++) {
        int m = m0 + wm + mt * 16 + q * 4 + rr;
        float vv = acc[mt][nt][rr];
        if (m < M && n < N) {
          if (DEC) {
            vv += bias[n];
            int tt = m >> 5, bb = m & 31;
            outp[((size_t)bb * 719 + tt) * 6000 + n] = vv;
          } else {
            outp[(size_t)m * 1024 + n] = vv;
          }
        }
      }
    }
  }
}

// ---------------------------------------------------------------------------
// K3: LSTM recurrence. 8 WGs x 512 threads. WG wg owns h-cols [wg*32, wg*32+32)
// => 128 gate rows of Whh (bf16 MFMA A-fragments, persistent in VGPRs).
// Sync: NO flags, NO fences, NO acks. Validity travels WITH the data:
// Htag[t][b][d/2] is one u64 = (tag=t+1)<<32 | (2 bf16 h-values). A single
// relaxed agent-scope 8-B atomic load returns tag+payload atomically, so the
// consumer poll IS the data load (detect and load legs merged), and the
// producer just fires one 8-B store and moves on (no vmcnt ack, no flag leg).
// Addresses are fresh per t => no in-launch staleness; the per-launch memset
// of Htag kills cross-launch tag reuse (launch N+1 sees zeros, never launch
// N's identical tags).
// ---------------------------------------------------------------------------
__global__ __launch_bounds__(512) void rnn719(
    const float* __restrict__ Whh, const int* __restrict__ cmt,
    const float* __restrict__ Z0, const float* __restrict__ XW,
    const float* __restrict__ bih, const float* __restrict__ bhh,
    u64* __restrict__ Htag) {
  const int tid = threadIdx.x, wg = blockIdx.x;
  const int j0 = wg * 32;
  const int w = tid >> 6, l = tid & 63, ln = l & 15, q = l >> 4;
  const int ntile = w & 1, mpair = w >> 1;
  __shared__ __align__(16) u16 hs[32 * 264];     // h_{t-1}, padded stride
  __shared__ __align__(16) float gbuf[128 * 33]; // Whh@h partial gates

  // persistent A-fragments: A[m=lane&15][k=q*8+j]
  bf16x8 afr[2][8];
#pragma unroll
  for (int mt = 0; mt < 2; mt++) {
    int mu = (mpair * 2 + mt) * 16 + ln;   // local gate-row index [0,128)
    int gate = mu >> 5, jj = mu & 31;
    const float* rp = Whh + (size_t)(gate * 256 + j0 + jj) * 256;
#pragma unroll
    for (int kk = 0; kk < 8; kk++) {
      union { u16 t[8]; bf16x8 v; } u;
#pragma unroll
      for (int e = 0; e < 8; e++) u.t[e] = f2bf(rp[kk * 32 + q * 8 + e]);
      afr[mt][kk] = u.v;
    }
  }

  // gate-phase mapping: thread -> (batch gb, j-pair jp)
  const int gb = tid >> 4;
  const int jp = (tid & 15) * 2;
  float bs[4][2];
#pragma unroll
  for (int gt = 0; gt < 4; gt++) {
    bs[gt][0] = bih[gt * 256 + j0 + jp] + bhh[gt * 256 + j0 + jp];
    bs[gt][1] = bih[gt * 256 + j0 + jp + 1] + bhh[gt * 256 + j0 + jp + 1];
  }
  float c2[2] = {0.f, 0.f};

  // this thread's output word: Htag[t][gb][(j0+jp)/2]
  const int myword = gb * 128 + wg * 16 + (tid & 15);

  for (int t = 0; t < 719; t++) {
    // x-part gather: Z0 at t=0, XWvocab[token] else, 0 if masked
    // (issued before the poll so the XW latency hides under the wait)
    float zv[4][2];
    const float* base = nullptr;
    if (t == 0) {
      base = Z0 + gb * 1024;
    } else {
      int idx = cmt[gb * 719 + t];
      if (idx >= 0) base = XW + (size_t)idx * 1024;
    }
    if (base) {
#pragma unroll
      for (int gt = 0; gt < 4; gt++) {
        f32x2 v2 = *(const f32x2*)(base + gt * 256 + j0 + jp);
        zv[gt][0] = v2[0]; zv[gt][1] = v2[1];
      }
    } else {
#pragma unroll
      for (int gt = 0; gt < 4; gt++) { zv[gt][0] = 0.f; zv[gt][1] = 0.f; }
    }

    if (t > 0) {
      // poll h_{t-1}: 8 tagged u64 per thread; tag match == data valid.
      const u64* hp = Htag + (size_t)(t - 1) * 4096;
      const u32 expt = (u32)t;   // stored tag was (t-1)+1
      u64 vals[8];
      int guard = 0;
      for (;;) {
        bool ok = true;
#pragma unroll
        for (int i = 0; i < 8; i++)
          vals[i] = __hip_atomic_load(hp + tid + i * 512, __ATOMIC_RELAXED,
                                      __HIP_MEMORY_SCOPE_AGENT);
#pragma unroll
        for (int i = 0; i < 8; i++) ok &= ((u32)(vals[i] >> 32) == expt);
        if (ok) break;
        if (++guard > (1 << 20)) break;  // safety valve vs hang
      }
      // stage into LDS (strip tags)
#pragma unroll
      for (int i = 0; i < 8; i++) {
        int ch = tid + i * 512;
        int row = ch >> 7, dp = ch & 127;
        *(u32*)&hs[row * 264 + dp * 2] = (u32)vals[i];
      }
      __syncthreads();
      // D[m=gate-row][n=batch] = Whh_slice @ h
      f32x4 a0 = {0.f, 0.f, 0.f, 0.f}, a1 = a0;
#pragma unroll
      for (int kk = 0; kk < 8; kk++) {
        bf16x8 bfr = ld8(&hs[(ntile * 16 + ln) * 264 + kk * 32 + q * 8]);
        a0 = MFMA16(afr[0][kk], bfr, a0);
        a1 = MFMA16(afr[1][kk], bfr, a1);
      }
#pragma unroll
      for (int rr = 0; rr < 4; rr++) {
        gbuf[((mpair * 2 + 0) * 16 + q * 4 + rr) * 33 + ntile * 16 + ln] = a0[rr];
        gbuf[((mpair * 2 + 1) * 16 + q * 4 + rr) * 33 + ntile * 16 + ln] = a1[rr];
      }
      __syncthreads();
    }

    // gates, c/h update for this WG's 32 j-columns
    u32 hpk = 0;
#pragma unroll
    for (int pj = 0; pj < 2; pj++) {
      int j = jp + pj;
      float gi = zv[0][pj] + bs[0][pj];
      float gf = zv[1][pj] + bs[1][pj];
      float gg = zv[2][pj] + bs[2][pj];
      float go = zv[3][pj] + bs[3][pj];
      if (t > 0) {
        gi += gbuf[(j) * 33 + gb];
        gf += gbuf[(32 + j) * 33 + gb];
        gg += gbuf[(64 + j) * 33 + gb];
        go += gbuf[(96 + j) * 33 + gb];
      }
      float ii = sigm(gi);
      float ff = sigm(gf);
      float g2 = tanh_f(gg);
      float oo = sigm(go);
      float cc = ff * c2[pj] + ii * g2;
      c2[pj] = cc;
      float hh = oo * tanh_f(cc);
      hpk |= ((u32)f2bf(hh)) << (16 * pj);
    }
    // publish: ONE tagged u64, fire-and-forget (atomicity of the 8-B word
    // makes tag==valid imply payload present; no ordering needed).
    __hip_atomic_store(Htag + (size_t)t * 4096 + myword,
                       ((u64)(u32)(t + 1) << 32) | (u64)hpk,
                       __ATOMIC_RELAXED, __HIP_MEMORY_SCOPE_AGENT);
  }
}

// ---------------------------------------------------------------------------
extern "C" void kernel_launch(void* const* d_in, const int* in_sizes, int n_in,
                              void* d_out, int out_size, void* d_ws, size_t ws_size,
                              hipStream_t stream) {
  const float* board = (const float*)d_in[0];
  const int*   cmt   = (const int*)d_in[1];
  const float* convk = (const float*)d_in[2];
  const float* convb = (const float*)d_in[3];
  const float* gma   = (const float*)d_in[4];
  const float* bta   = (const float*)d_in[5];
  const float* embed = (const float*)d_in[6];
  const float* linW  = (const float*)d_in[7];
  const float* linb  = (const float*)d_in[8];
  const float* Wih   = (const float*)d_in[9];
  const float* Whh   = (const float*)d_in[10];
  const float* bihp  = (const float*)d_in[11];
  const float* bhhp  = (const float*)d_in[12];
  const float* decW  = (const float*)d_in[13];
  const float* decb  = (const float*)d_in[14];

  char* ws = (char*)d_ws;
  float* Z0     = (float*)(ws + 0);                  // 32*1024 f32      ->    131,072
  float* XW     = (float*)(ws + 131072);             // 6000*1024 f32    -> 24,707,072
  u64*  Htag    = (u64*)(ws + 24707072);             // 719*32*128 u64   -> 48,267,264
  u16*  embedB  = (u16*)(ws + 48267264);             // 6000*256 bf16    -> 51,339,264
  u16*  WihB    = (u16*)(ws + 51339264);             // 1024*256 bf16    -> 51,863,552
  u16*  decWB   = (u16*)(ws + 51863552);             // 6000*256 bf16    -> 54,935,552

  // cross-launch tag reuse would re-validate stale h: zero tags every launch
  hipMemsetAsync(Htag, 0, 23560192, stream);
  hipLaunchKernelGGL(castbf, dim3(1500), dim3(256), 0, stream, embed, embedB, 384000);
  hipLaunchKernelGGL(castbf, dim3(256),  dim3(256), 0, stream, Wih,   WihB,   65536);
  hipLaunchKernelGGL(castbf, dim3(1500), dim3(256), 0, stream, decW,  decWB,  384000);
  hipLaunchKernelGGL(k1_tower, dim3(32), dim3(384), 0, stream,
                     board, convk, convb, gma, bta, linW, linb, Wih, Z0);
  hipLaunchKernelGGL((gemm_k256<0>), dim3(8, 47), dim3(256), 0, stream,
                     embedB, WihB, (const float*)nullptr, XW, 6000, 1024);
  hipLaunchKernelGGL(rnn719, dim3(8), dim3(512), 0, stream,
                     Whh, cmt, Z0, XW, bihp, bhhp, Htag);
  hipLaunchKernelGGL((gemm_k256<1>), dim3(47, 180), dim3(256), 0, stream,
                     (const u16*)Htag, decWB, decb, (float*)d_out, 23008, 6000);
  (void)in_sizes; (void)n_in; (void)out_size; (void)ws_size;
}

// Round 5
// 2527.888 us; speedup vs baseline: 1.8167x; 1.0747x over previous
//
#include <hip/hip_runtime.h>
#include <hip/hip_bf16.h>
#include <stdint.h>

typedef unsigned short u16;
typedef unsigned int u32;
typedef unsigned long long u64;
typedef float f32x4 __attribute__((ext_vector_type(4)));
typedef float f32x2 __attribute__((ext_vector_type(2)));
typedef u32 u32x4 __attribute__((ext_vector_type(4)));
typedef __bf16 bf16x8 __attribute__((ext_vector_type(8)));

#define MFMA16(A, B, C) __builtin_amdgcn_mfma_f32_16x16x32_bf16((A), (B), (C), 0, 0, 0)

__device__ __forceinline__ u16 f2bf(float f) {
  u32 u = __float_as_uint(f);
  u32 r = (u + 0x7fffu + ((u >> 16) & 1u)) >> 16;
  return (u16)r;
}
__device__ __forceinline__ bf16x8 ld8(const u16* p) {
  return __builtin_bit_cast(bf16x8, *(const u32x4*)p);
}
// fast sigmoid/tanh via v_exp; safe for all finite inputs
__device__ __forceinline__ float sigm(float x) { return 1.f / (1.f + __expf(-x)); }
__device__ __forceinline__ float tanh_f(float x) {
  float a = fabsf(x);
  float e = __expf(-2.f * a);          // e in (0,1], never overflows
  float r = (1.f - e) / (1.f + e);
  return copysignf(r, x);
}

// ---------------------------------------------------------------------------
// cast f32 -> bf16 (RNE), 4 elems/thread
// ---------------------------------------------------------------------------
__global__ __launch_bounds__(256) void castbf(const float* __restrict__ s,
                                              u16* __restrict__ d, int n4) {
  int i = blockIdx.x * 256 + threadIdx.x;
  if (i >= n4) return;
  f32x4 v = *(const f32x4*)(s + (size_t)i * 4);
  union { u16 t[4]; u64 v; } u;
#pragma unroll
  for (int e = 0; e < 4; e++) u.t[e] = f2bf(v[e]);
  *(u64*)(d + (size_t)i * 4) = u.v;
}

// ---------------------------------------------------------------------------
// K1: conv tower (8x conv+instance-norm, residuals) + feat + Z0 = feat@Wih.T
// one workgroup per batch image (32 WGs x 384 threads), all f32
// ---------------------------------------------------------------------------
__device__ __forceinline__ float cbn_step(float* cur, float* red, int tid, int r, int c,
                                          bool act, const float* kk, float cb, float gm,
                                          float bt, int w, int l) {
  float y = 0.f;
  if (act) {
#pragma unroll
    for (int dr = -1; dr <= 1; dr++) {
#pragma unroll
      for (int dc = -1; dc <= 1; dc++) {
        int rr = r + dr, cc = c + dc;
        if (rr >= 0 && rr < 19 && cc >= 0 && cc < 19)
          y += cur[rr * 19 + cc] * kk[(dr + 1) * 3 + (dc + 1)];
      }
    }
    y += cb;
  }
  float s = act ? y : 0.f;
  float s2 = act ? y * y : 0.f;
#pragma unroll
  for (int o = 32; o >= 1; o >>= 1) {
    s += __shfl_xor(s, o);
    s2 += __shfl_xor(s2, o);
  }
  if (l == 0) { red[w] = s; red[8 + w] = s2; }
  __syncthreads();
  if (tid == 0) {
    float sa = 0.f, sb = 0.f;
    for (int i = 0; i < 6; i++) { sa += red[i]; sb += red[8 + i]; }
    float m = sa * (1.f / 361.f);
    float v = sb * (1.f / 361.f) - m * m;
    red[14] = m;
    red[15] = rsqrtf(v + 1e-5f) * gm;
  }
  __syncthreads();
  float m = red[14], sc = red[15];
  return act ? ((y - m) * sc + bt) : 0.f;
}

__global__ __launch_bounds__(384) void k1_tower(
    const float* __restrict__ board, const float* __restrict__ convk,
    const float* __restrict__ convb, const float* __restrict__ gma,
    const float* __restrict__ bta, const float* __restrict__ linW,
    const float* __restrict__ linb, const float* __restrict__ Wih,
    float* __restrict__ Z0) {
  const int b = blockIdx.x, tid = threadIdx.x;
  const int w = tid >> 6, l = tid & 63;
  __shared__ __align__(16) float cur[361];
  __shared__ __align__(16) float red[16];
  __shared__ __align__(16) float fs[256];
  const bool act = tid < 361;
  const int r = tid / 19, c = tid - r * 19;
  float kk[9];
#pragma unroll
  for (int i = 0; i < 9; i++) kk[i] = convk[i];
  const float cb = convb[0], gm = gma[0], bt = bta[0];
  if (act) cur[tid] = board[b * 361 + tid];
  __syncthreads();

  float v = cbn_step(cur, red, tid, r, c, act, kk, cb, gm, bt, w, l);
  float d2v = fmaxf(v, 0.f);
  if (act) cur[tid] = d2v;
  __syncthreads();
  for (int it = 0; it < 3; it++) {
    v = cbn_step(cur, red, tid, r, c, act, kk, cb, gm, bt, w, l);
    if (act) cur[tid] = fmaxf(v, 0.f);
    __syncthreads();
    v = cbn_step(cur, red, tid, r, c, act, kk, cb, gm, bt, w, l);
    float nv = fmaxf(v + d2v, 0.f);
    if (act) cur[tid] = nv;
    d2v = nv;
    __syncthreads();
  }
  v = cbn_step(cur, red, tid, r, c, act, kk, cb, gm, bt, w, l);
  if (act) cur[tid] = fmaxf(v, 0.f);
  __syncthreads();

  // feat[d] = sum_p d1[p]*lin_W[d][p] + lin_b[d]
  if (tid < 256) {
    float f = linb[tid];
    const float* wr = linW + tid * 361;
    for (int p = 0; p < 361; p++) f += cur[p] * wr[p];
    fs[tid] = f;
  }
  __syncthreads();
  // Z0[b][r] = sum_k feat[k]*Wih[r][k]   (full f32)
  for (int rr = tid; rr < 1024; rr += 384) {
    const float* wr = Wih + rr * 256;
    float z = 0.f;
#pragma unroll 4
    for (int k2 = 0; k2 < 256; k2++) z += fs[k2] * wr[k2];
    Z0[b * 1024 + rr] = z;
  }
}

// ---------------------------------------------------------------------------
// GEMM (XW precompute): C[m][n] = sum_k A[m][k]*W[n][k], K=256, A/W bf16,
// out f32 row stride 1024. 256 threads.
// ---------------------------------------------------------------------------
__global__ __launch_bounds__(256) void gemm_k256(
    const u16* __restrict__ A, const u16* __restrict__ W,
    float* __restrict__ outp, int M, int N) {
  __shared__ __align__(16) u16 As[128 * 72];
  __shared__ __align__(16) u16 Ws[128 * 72];
  const int tid = threadIdx.x;
  const int w = tid >> 6, l = tid & 63, ln = l & 15, q = l >> 4;
  const int wm = (w >> 1) * 64, wn = (w & 1) * 64;
  const int m0 = blockIdx.y * 128, n0 = blockIdx.x * 128;
  f32x4 zero4 = {0.f, 0.f, 0.f, 0.f};
  f32x4 acc[4][4];
#pragma unroll
  for (int i = 0; i < 4; i++)
#pragma unroll
    for (int j = 0; j < 4; j++) acc[i][j] = zero4;

  for (int kb = 0; kb < 4; kb++) {
    if (kb) __syncthreads();
#pragma unroll
    for (int i = 0; i < 4; i++) {
      int ch = tid + i * 256;
      int row = ch >> 3, cj = ch & 7;
      int ga = m0 + row; if (ga > M - 1) ga = M - 1;
      int gw = n0 + row; if (gw > N - 1) gw = N - 1;
      *(u32x4*)&As[row * 72 + cj * 8] = *(const u32x4*)(A + (size_t)ga * 256 + kb * 64 + cj * 8);
      *(u32x4*)&Ws[row * 72 + cj * 8] = *(const u32x4*)(W + (size_t)gw * 256 + kb * 64 + cj * 8);
    }
    __syncthreads();
#pragma unroll
    for (int kk = 0; kk < 2; kk++) {
      bf16x8 af[4], wf[4];
#pragma unroll
      for (int mt = 0; mt < 4; mt++) af[mt] = ld8(&As[(wm + mt * 16 + ln) * 72 + kk * 32 + q * 8]);
#pragma unroll
      for (int nt = 0; nt < 4; nt++) wf[nt] = ld8(&Ws[(wn + nt * 16 + ln) * 72 + kk * 32 + q * 8]);
#pragma unroll
      for (int mt = 0; mt < 4; mt++)
#pragma unroll
        for (int nt = 0; nt < 4; nt++) acc[mt][nt] = MFMA16(af[mt], wf[nt], acc[mt][nt]);
    }
  }
#pragma unroll
  for (int mt = 0; mt < 4; mt++) {
#pragma unroll
    for (int nt = 0; nt < 4; nt++) {
      int n = n0 + wn + nt * 16 + ln;
#pragma unroll
      for (int rr = 0; rr < 4; rr++) {
        int m = m0 + wm + mt * 16 + q * 4 + rr;
        if (m < M && n < N) outp[(size_t)m * 1024 + n] = acc[mt][nt][rr];
      }
    }
  }
}

// ---------------------------------------------------------------------------
// FUSED K3: LSTM recurrence (blocks 0..7) + decode GEMM (blocks 8..255).
// Grid 256 x 512thr: <=36.9KB LDS, VGPR<256 => every WG resident (1/CU) =>
// producer/consumer co-residency WITHOUT cooperative launch, no deadlock.
//
// Recurrence: round-3 proven sc1 tagged-word transport. Htag[t][b][d/2] u64 =
// (tag=t+1)<<32 | 2 bf16. Poll IS the data load; no fences/flags/acks.
//
// Decoder: tile (by,bx) of out needs steps <= tmax=min(4by+3,718). Sentinel:
// a valid tag on ANY word of step s implies ALL steps < s are visible at the
// coherence point (its producer polled all of step s-1 to completion before
// storing step s; CP values persist). Step 718 is covered by 8 per-WG done
// words published after per-wave vmcnt(0) + __syncthreads. Decoder A-reads
// use sc1 atomic loads (CP-direct; no stale-L2 exposure inside one kernel).
// ---------------------------------------------------------------------------
union __align__(16) SharedU {
  struct { u16 hs[32 * 264]; float gbuf[128 * 33]; } r;   // rnn: 33,792 B
  struct { u16 As[128 * 72]; u16 Ws[128 * 72]; } d;       // dec: 36,864 B
};

__device__ void rnn_body(SharedU& sm,
    const float* __restrict__ Whh, const int* __restrict__ cmt,
    const float* __restrict__ Z0, const float* __restrict__ XW,
    const float* __restrict__ bih, const float* __restrict__ bhh,
    u64* __restrict__ Htag, u64* __restrict__ Hdone) {
  const int tid = threadIdx.x, wg = blockIdx.x;
  const int j0 = wg * 32;
  const int w = tid >> 6, l = tid & 63, ln = l & 15, q = l >> 4;
  const int ntile = w & 1, mpair = w >> 1;
  u16* hs = sm.r.hs;
  float* gbuf = sm.r.gbuf;

  // persistent A-fragments: A[m=lane&15][k=q*8+j]
  bf16x8 afr[2][8];
#pragma unroll
  for (int mt = 0; mt < 2; mt++) {
    int mu = (mpair * 2 + mt) * 16 + ln;   // local gate-row index [0,128)
    int gate = mu >> 5, jj = mu & 31;
    const float* rp = Whh + (size_t)(gate * 256 + j0 + jj) * 256;
#pragma unroll
    for (int kk = 0; kk < 8; kk++) {
      union { u16 t[8]; bf16x8 v; } u;
#pragma unroll
      for (int e = 0; e < 8; e++) u.t[e] = f2bf(rp[kk * 32 + q * 8 + e]);
      afr[mt][kk] = u.v;
    }
  }

  // gate-phase mapping: thread -> (batch gb, j-pair jp)
  const int gb = tid >> 4;
  const int jp = (tid & 15) * 2;
  float bs[4][2];
#pragma unroll
  for (int gt = 0; gt < 4; gt++) {
    bs[gt][0] = bih[gt * 256 + j0 + jp] + bhh[gt * 256 + j0 + jp];
    bs[gt][1] = bih[gt * 256 + j0 + jp + 1] + bhh[gt * 256 + j0 + jp + 1];
  }
  float c2[2] = {0.f, 0.f};

  const int myword = gb * 128 + wg * 16 + (tid & 15);

  for (int t = 0; t < 719; t++) {
    float zv[4][2];
    const float* base = nullptr;
    if (t == 0) {
      base = Z0 + gb * 1024;
    } else {
      int idx = cmt[gb * 719 + t];
      if (idx >= 0) base = XW + (size_t)idx * 1024;
    }
    if (base) {
#pragma unroll
      for (int gt = 0; gt < 4; gt++) {
        f32x2 v2 = *(const f32x2*)(base + gt * 256 + j0 + jp);
        zv[gt][0] = v2[0]; zv[gt][1] = v2[1];
      }
    } else {
#pragma unroll
      for (int gt = 0; gt < 4; gt++) { zv[gt][0] = 0.f; zv[gt][1] = 0.f; }
    }

    if (t > 0) {
      // poll h_{t-1}: 8 tagged u64 per thread; tag match == data valid.
      const u64* hp = Htag + (size_t)(t - 1) * 4096;
      const u32 expt = (u32)t;
      u64 vals[8];
      int guard = 0;
      for (;;) {
        bool ok = true;
#pragma unroll
        for (int i = 0; i < 8; i++)
          vals[i] = __hip_atomic_load(hp + tid + i * 512, __ATOMIC_RELAXED,
                                      __HIP_MEMORY_SCOPE_AGENT);
#pragma unroll
        for (int i = 0; i < 8; i++) ok &= ((u32)(vals[i] >> 32) == expt);
        if (ok) break;
        if (++guard > (1 << 20)) break;  // safety valve vs hang
      }
      // stage into LDS (strip tags)
#pragma unroll
      for (int i = 0; i < 8; i++) {
        int ch = tid + i * 512;
        int row = ch >> 7, dp = ch & 127;
        *(u32*)&hs[row * 264 + dp * 2] = (u32)vals[i];
      }
      __syncthreads();
      // D[m=gate-row][n=batch] = Whh_slice @ h
      f32x4 a0 = {0.f, 0.f, 0.f, 0.f}, a1 = a0;
#pragma unroll
      for (int kk = 0; kk < 8; kk++) {
        bf16x8 bfr = ld8(&hs[(ntile * 16 + ln) * 264 + kk * 32 + q * 8]);
        a0 = MFMA16(afr[0][kk], bfr, a0);
        a1 = MFMA16(afr[1][kk], bfr, a1);
      }
#pragma unroll
      for (int rr = 0; rr < 4; rr++) {
        gbuf[((mpair * 2 + 0) * 16 + q * 4 + rr) * 33 + ntile * 16 + ln] = a0[rr];
        gbuf[((mpair * 2 + 1) * 16 + q * 4 + rr) * 33 + ntile * 16 + ln] = a1[rr];
      }
      __syncthreads();
    }

    // gates, c/h update for this WG's 32 j-columns
    u32 hpk = 0;
#pragma unroll
    for (int pj = 0; pj < 2; pj++) {
      int j = jp + pj;
      float gi = zv[0][pj] + bs[0][pj];
      float gf = zv[1][pj] + bs[1][pj];
      float gg = zv[2][pj] + bs[2][pj];
      float go = zv[3][pj] + bs[3][pj];
      if (t > 0) {
        gi += gbuf[(j) * 33 + gb];
        gf += gbuf[(32 + j) * 33 + gb];
        gg += gbuf[(64 + j) * 33 + gb];
        go += gbuf[(96 + j) * 33 + gb];
      }
      float ii = sigm(gi);
      float ff = sigm(gf);
      float g2 = tanh_f(gg);
      float oo = sigm(go);
      float cc = ff * c2[pj] + ii * g2;
      c2[pj] = cc;
      float hh = oo * tanh_f(cc);
      hpk |= ((u32)f2bf(hh)) << (16 * pj);
    }
    __hip_atomic_store(Htag + (size_t)t * 4096 + myword,
                       ((u64)(u32)(t + 1) << 32) | (u64)hpk,
                       __ATOMIC_RELAXED, __HIP_MEMORY_SCOPE_AGENT);
  }
  // final: make step-718 visibility provable for the decoder.
  asm volatile("s_waitcnt vmcnt(0)" ::: "memory");  // per-wave: its stores at CP
  __syncthreads();                                  // all waves past vmcnt(0)
  if (tid == 0)
    __hip_atomic_store(Hdone + wg, ((u64)720u << 32), __ATOMIC_RELAXED,
                       __HIP_MEMORY_SCOPE_AGENT);
}

__device__ void decode_body(SharedU& sm,
    const u64* __restrict__ Htag, const u64* __restrict__ Hdone,
    const u16* __restrict__ W, const float* __restrict__ bias,
    float* __restrict__ outp, int worker) {
  const int tid = threadIdx.x;
  const int w = tid >> 6, l = tid & 63, ln = l & 15, q = l >> 4;
  const int wm = (w >> 2) * 64, wn = (w & 3) * 32;  // 8 waves: 2m x 4n of 64x32
  const int M = 23008, N = 6000;
  u16* As = sm.d.As;
  u16* Ws = sm.d.Ws;

  for (int tau = worker; tau < 47 * 180; tau += 248) {
    const int by = tau / 47, bx = tau - by * 47;
    const int m0 = by * 128, n0 = bx * 128;
    int tmax = (m0 + 127) >> 5; if (tmax > 718) tmax = 718;

    // sentinel wait (thread 0), then barrier (also guards LDS reuse)
    if (tid == 0) {
      int guard = 0;
      if (tmax < 718) {
        const u64* sp = Htag + (size_t)(tmax + 1) * 4096;
        while ((u32)(__hip_atomic_load(sp, __ATOMIC_RELAXED,
                                       __HIP_MEMORY_SCOPE_AGENT) >> 32) !=
               (u32)(tmax + 2)) {
          if (++guard > (1 << 22)) break;
        }
      } else {
        for (int i = 0; i < 8; i++) {
          guard = 0;
          while ((u32)(__hip_atomic_load(Hdone + i, __ATOMIC_RELAXED,
                                         __HIP_MEMORY_SCOPE_AGENT) >> 32) != 720u) {
            if (++guard > (1 << 22)) break;
          }
        }
      }
    }
    __syncthreads();

    f32x4 zero4 = {0.f, 0.f, 0.f, 0.f};
    f32x4 acc[4][2];
#pragma unroll
    for (int i = 0; i < 4; i++) { acc[i][0] = zero4; acc[i][1] = zero4; }

    for (int kb = 0; kb < 4; kb++) {
      if (kb) __syncthreads();
#pragma unroll
      for (int i = 0; i < 2; i++) {
        int ch = tid + i * 512;
        int row = ch >> 3, cj = ch & 7;
        int ga = m0 + row; if (ga > M - 1) ga = M - 1;
        int gw = n0 + row; if (gw > N - 1) gw = N - 1;
        // tagged A via sc1 (CP-direct) loads; strip high32 tags
        const u64* ap = Htag + (size_t)ga * 128 + kb * 32 + cj * 4;
        u64 w0 = __hip_atomic_load(ap + 0, __ATOMIC_RELAXED, __HIP_MEMORY_SCOPE_AGENT);
        u64 w1 = __hip_atomic_load(ap + 1, __ATOMIC_RELAXED, __HIP_MEMORY_SCOPE_AGENT);
        u64 w2 = __hip_atomic_load(ap + 2, __ATOMIC_RELAXED, __HIP_MEMORY_SCOPE_AGENT);
        u64 w3 = __hip_atomic_load(ap + 3, __ATOMIC_RELAXED, __HIP_MEMORY_SCOPE_AGENT);
        u32 pk[4] = {(u32)w0, (u32)w1, (u32)w2, (u32)w3};
        *(u32x4*)&As[row * 72 + cj * 8] = *(const u32x4*)pk;
        *(u32x4*)&Ws[row * 72 + cj * 8] = *(const u32x4*)(W + (size_t)gw * 256 + kb * 64 + cj * 8);
      }
      __syncthreads();
#pragma unroll
      for (int kk = 0; kk < 2; kk++) {
        bf16x8 af[4], wf[2];
#pragma unroll
        for (int mt = 0; mt < 4; mt++) af[mt] = ld8(&As[(wm + mt * 16 + ln) * 72 + kk * 32 + q * 8]);
#pragma unroll
        for (int nt = 0; nt < 2; nt++) wf[nt] = ld8(&Ws[(wn + nt * 16 + ln) * 72 + kk * 32 + q * 8]);
#pragma unroll
        for (int mt = 0; mt < 4; mt++)
#pragma unroll
          for (int nt = 0; nt < 2; nt++) acc[mt][nt] = MFMA16(af[mt], wf[nt], acc[mt][nt]);
      }
    }
    // epilogue: col(n)=lane&15, row(m)=q*4+rr; out row permutation m=tt*32+bb
#pragma unroll
    for (int mt = 0; mt < 4; mt++) {
#pragma unroll
      for (int nt = 0; nt < 2; nt++) {
        int n = n0 + wn + nt * 16 + ln;
#pragma unroll
        for (int rr = 0; rr < 4; rr++) {
          int m = m0 + wm + mt * 16 + q * 4 + rr;
          if (m < M && n < N) {
            float vv = acc[mt][nt][rr] + bias[n];
            int tt = m >> 5, bb = m & 31;
            outp[((size_t)bb * 719 + tt) * 6000 + n] = vv;
          }
        }
      }
    }
    __syncthreads();  // MFMA LDS reads done before next tile's staging
  }
}

__global__ __launch_bounds__(512) void rnn719(
    const float* __restrict__ Whh, const int* __restrict__ cmt,
    const float* __restrict__ Z0, const float* __restrict__ XW,
    const float* __restrict__ bih, const float* __restrict__ bhh,
    u64* __restrict__ Htag, u64* __restrict__ Hdone,
    const u16* __restrict__ decW, const float* __restrict__ decb,
    float* __restrict__ outp) {
  __shared__ SharedU sm;
  if (blockIdx.x < 8) {
    rnn_body(sm, Whh, cmt, Z0, XW, bih, bhh, Htag, Hdone);
  } else {
    decode_body(sm, Htag, Hdone, decW, decb, outp, blockIdx.x - 8);
  }
}

// ---------------------------------------------------------------------------
extern "C" void kernel_launch(void* const* d_in, const int* in_sizes, int n_in,
                              void* d_out, int out_size, void* d_ws, size_t ws_size,
                              hipStream_t stream) {
  const float* board = (const float*)d_in[0];
  const int*   cmt   = (const int*)d_in[1];
  const float* convk = (const float*)d_in[2];
  const float* convb = (const float*)d_in[3];
  const float* gma   = (const float*)d_in[4];
  const float* bta   = (const float*)d_in[5];
  const float* embed = (const float*)d_in[6];
  const float* linW  = (const float*)d_in[7];
  const float* linb  = (const float*)d_in[8];
  const float* Wih   = (const float*)d_in[9];
  const float* Whh   = (const float*)d_in[10];
  const float* bihp  = (const float*)d_in[11];
  const float* bhhp  = (const float*)d_in[12];
  const float* decW  = (const float*)d_in[13];
  const float* decb  = (const float*)d_in[14];

  char* ws = (char*)d_ws;
  float* Z0     = (float*)(ws + 0);                  // 32*1024 f32      ->    131,072
  float* XW     = (float*)(ws + 131072);             // 6000*1024 f32    -> 24,707,072
  u64*  Htag    = (u64*)(ws + 24707072);             // 719*32*128 u64   -> 48,267,264
  u64*  Hdone   = (u64*)(ws + 48267264);             // 8 u64            -> 48,267,328
  u16*  embedB  = (u16*)(ws + 48267328);             // 6000*256 bf16    -> 51,339,328
  u16*  WihB    = (u16*)(ws + 51339328);             // 1024*256 bf16    -> 51,863,616
  u16*  decWB   = (u16*)(ws + 51863616);             // 6000*256 bf16    -> 54,935,616

  // cross-launch tag reuse would re-validate stale h: zero tags + done words
  hipMemsetAsync(Htag, 0, 23560256, stream);
  hipLaunchKernelGGL(castbf, dim3(1500), dim3(256), 0, stream, embed, embedB, 384000);
  hipLaunchKernelGGL(castbf, dim3(256),  dim3(256), 0, stream, Wih,   WihB,   65536);
  hipLaunchKernelGGL(castbf, dim3(1500), dim3(256), 0, stream, decW,  decWB,  384000);
  hipLaunchKernelGGL(k1_tower, dim3(32), dim3(384), 0, stream,
                     board, convk, convb, gma, bta, linW, linb, Wih, Z0);
  hipLaunchKernelGGL(gemm_k256, dim3(8, 47), dim3(256), 0, stream,
                     embedB, WihB, XW, 6000, 1024);
  hipLaunchKernelGGL(rnn719, dim3(256), dim3(512), 0, stream,
                     Whh, cmt, Z0, XW, bihp, bhhp, Htag, Hdone,
                     decWB, decb, (float*)d_out);
  (void)in_sizes; (void)n_in; (void)out_size; (void)ws_size;
}